// Round 5
// baseline (307.134 us; speedup 1.0000x reference)
//
#include <hip/hip_runtime.h>

// Problem constants (from reference): S=56, B=5, C=20, N=128
constexpr int S_   = 56;
constexpr int B_   = 5;
constexpr int C_   = 20;
constexpr int N_   = 128;
constexpr int CELLS = N_ * S_ * S_;   // 401408
constexpr int PSTR  = B_ * (C_ + 5);  // 125 floats per cell (predicts)
constexpr int TSTR  = C_ + 5;         // 25 floats per cell (targets)

constexpr int GCELL  = 16;                  // cells per group
constexpr int NGROUP = CELLS / GCELL;       // 25088
constexpr int GRID   = 1792;                // 7 blocks/CU * 256 CU
constexpr int GPBK   = NGROUP / GRID;       // 14 groups per block, exact
constexpr int GP_B   = GCELL * PSTR * 4;    // 8000 B pred per group
constexpr int GT_B   = GCELL * TSTR * 4;    // 1600 B targ per group
constexpr int BUF_B  = GP_B + GT_B;         // 9600 B per buffer
// LDS = 2 buffers = 19200 B -> 8 fit/CU; grid places 7/CU. PERSISTENT
// blocks: each owns a contiguous 14-group (134 KB) run. Counted-vmcnt
// ping-pong keeps 10-20 DMA ops (9.6-19.2 KB) in flight per wave at ALL
// times (no drain-to-zero until the last group, no block relaunch gaps).
// Exactly 10 VMEM ops per group -> counted waits are exact.

// async global->LDS, 16 B per lane. LDS dest = wave-uniform base + lane*16.
__device__ __forceinline__ void gload_lds16(const char* g, char* l) {
    __builtin_amdgcn_global_load_lds(
        (const __attribute__((address_space(1))) void*)g,
        (__attribute__((address_space(3))) void*)l,
        16, 0, 0);
}

#define WAITVM(N) asm volatile("s_waitcnt vmcnt(" #N ")" ::: "memory")

// Stage one 16-cell group: 8 pred ops + 2 targ ops = 10 VMEM ops, always.
__device__ __forceinline__ void stage_group(const float* __restrict__ pred,
                                            const float* __restrict__ targ,
                                            int g, char* buf, int lane) {
    const char* gp = (const char*)(pred + (size_t)g * GCELL * PSTR);  // 8000 B
    const char* gt = (const char*)(targ + (size_t)g * GCELL * TSTR);  // 1600 B
    #pragma unroll
    for (int it = 0; it < 7; ++it)                        // 7 * 1024 = 7168
        gload_lds16(gp + it * 1024 + lane * 16, buf + it * 1024);
    if (lane < 52)                                        // 832 B pred tail
        gload_lds16(gp + 7168 + lane * 16, buf + 7168);
    gload_lds16(gt + lane * 16, buf + GP_B);              // 1024 B
    if (lane < 36)                                        // 576 B targ tail
        gload_lds16(gt + 1024 + lane * 16, buf + GP_B + 1024);
}

// Per-cell loss from a staged buffer; lanes 0..15 each own one cell.
__device__ __forceinline__ float cell_loss(const char* buf, int lane,
                                           const float* aw, const float* ah) {
    const float* pc = (const float*)buf + (size_t)lane * PSTR;           // 125 preds
    const float* tp = (const float*)(buf + GP_B) + (size_t)lane * TSTR;  // 25 targs
    // 16 lanes, stride 125 dwords (odd): lane*125 mod 32 distinct -> no conflicts.

    const float tcx = tp[C_ + 1], tcy = tp[C_ + 2];
    const float tw  = tp[C_ + 3], th  = tp[C_ + 4];
    const float tx0 = tcx - 0.5f * tw, ty0 = tcy - 0.5f * th;
    const float tx1 = tcx + 0.5f * tw, ty1 = tcy + 0.5f * th;
    const float area_t = tw * th;

    float best_iou = -1.f;
    int   best_b = 0;
    float bcx = 0.f, bcy = 0.f, bw = 0.f, bh = 0.f;

    #pragma unroll
    for (int b = 0; b < B_; ++b) {
        const float rcx = pc[b * TSTR + C_ + 1];
        const float rcy = pc[b * TSTR + C_ + 2];
        const float rw  = pc[b * TSTR + C_ + 3];
        const float rh  = pc[b * TSTR + C_ + 4];

        const float cx = __builtin_amdgcn_rcpf(1.f + __expf(-rcx)); // sigmoid
        const float cy = __builtin_amdgcn_rcpf(1.f + __expf(-rcy));
        const float w  = __expf(rw) * aw[b];
        const float h  = __expf(rh) * ah[b];

        const float x0 = cx - 0.5f * w, y0 = cy - 0.5f * h;
        const float x1 = cx + 0.5f * w, y1 = cy + 0.5f * h;

        float wi = fminf(x1, tx1) - fmaxf(x0, tx0);
        float hi = fminf(y1, ty1) - fmaxf(y0, ty0);
        wi = fmaxf(wi, 0.f);
        hi = fmaxf(hi, 0.f);
        const float inter = wi * hi;
        const float iou = inter * __builtin_amdgcn_rcpf(w * h + area_t - inter);

        // jnp.argmax keeps FIRST max -> strict '>'
        const bool better = iou > best_iou;
        best_iou = better ? iou : best_iou;
        best_b   = better ? b   : best_b;
        bcx = better ? cx : bcx;
        bcy = better ? cy : bcy;
        bw  = better ? w  : bw;
        bh  = better ? h  : bh;
    }

    const float* pb = pc + best_b * TSTR;   // divergent LDS offset — fine

    // class SSE (pbest[...,0] scaled by best_idx per reference)
    float acc = 0.f;
    #pragma unroll
    for (int k = 0; k < C_; ++k) {
        float v = pb[k];
        if (k == 0) v *= (float)best_b;
        const float d = v - tp[k];
        acc = fmaf(d, d, acc);
    }

    // xy SSE (transformed)
    float d;
    d = bcx - tcx; acc = fmaf(d, d, acc);
    d = bcy - tcy; acc = fmaf(d, d, acc);

    // wh SSE: sign(x)*sqrt(|x|+1e-6); bw,bh > 0 always
    d = sqrtf(bw + 1e-6f) - tw; acc = fmaf(d, d, acc);
    d = sqrtf(bh + 1e-6f) - th; acc = fmaf(d, d, acc);

    // obj / noobj share (pbest[20]-t[20])^2
    const float e    = tp[C_];
    const float ne   = 1.f - e;
    const float dobj = pb[C_] - e;
    return e * e * acc + (e * e + ne * ne) * (dobj * dobj);
}

__global__ __launch_bounds__(64) void yolo_loss_kernel(
    const float* __restrict__ pred,
    const float* __restrict__ targ,
    const float* __restrict__ anch,   // [B,2]
    float* __restrict__ part)         // [GRID] partials in d_ws
{
    __shared__ char lds[2 * BUF_B];   // 19200 B

    const int lane = threadIdx.x;     // 0..63
    const int g0   = blockIdx.x * GPBK;

    char* bufA = lds;
    char* bufB = lds + BUF_B;

    // anchors: 10 uniform floats, L1-resident broadcast
    float aw[B_], ah[B_];
    #pragma unroll
    for (int b = 0; b < B_; ++b) { aw[b] = anch[2 * b]; ah[b] = anch[2 * b + 1]; }

    // ---- persistent counted-vmcnt ping-pong over 14 groups ----
    stage_group(pred, targ, g0 + 0, bufA, lane);   // 10 ops
    stage_group(pred, targ, g0 + 1, bufB, lane);   // 10 ops (20 out)

    float total = 0.f;

    #pragma unroll 1
    for (int k = 0; k < 6; ++k) {                  // groups 0..11, refills 2..13
        WAITVM(10);                                // A landed; B's 10 in flight
        if (lane < GCELL) total += cell_loss(bufA, lane, aw, ah);
        stage_group(pred, targ, g0 + 2 * k + 2, bufA, lane);
        WAITVM(10);                                // B landed; A's 10 in flight
        if (lane < GCELL) total += cell_loss(bufB, lane, aw, ah);
        stage_group(pred, targ, g0 + 2 * k + 3, bufB, lane);
    }
    WAITVM(10);                                    // group 12 landed
    if (lane < GCELL) total += cell_loss(bufA, lane, aw, ah);
    WAITVM(0);                                     // group 13 landed
    if (lane < GCELL) total += cell_loss(bufB, lane, aw, ah);

    // width-16 shuffle reduction (lanes 0..15 hold values), one plain store.
    // Overwrite semantics -> poison-safe, no memset, no atomics.
    #pragma unroll
    for (int off = 8; off > 0; off >>= 1)
        total += __shfl_down(total, off, 16);

    if (lane == 0)
        part[blockIdx.x] = total;
}

__global__ __launch_bounds__(1024) void finalize_kernel(
    const float* __restrict__ part, float* __restrict__ out)
{
    float v = 0.f;
    for (int i = threadIdx.x; i < GRID; i += 1024)   // 1792 floats, coalesced
        v += part[i];

    #pragma unroll
    for (int off = 32; off > 0; off >>= 1)
        v += __shfl_down(v, off, 64);

    __shared__ float ws[16];
    if ((threadIdx.x & 63) == 0) ws[threadIdx.x >> 6] = v;
    __syncthreads();
    if (threadIdx.x < 16) {
        float x = ws[threadIdx.x];
        #pragma unroll
        for (int off = 8; off > 0; off >>= 1)
            x += __shfl_down(x, off, 16);
        if (threadIdx.x == 0) out[0] = x;
    }
}

extern "C" void kernel_launch(void* const* d_in, const int* in_sizes, int n_in,
                              void* d_out, int out_size, void* d_ws, size_t ws_size,
                              hipStream_t stream) {
    const float* pred = (const float*)d_in[0];   // (N,S,S,B,C+5) f32
    const float* targ = (const float*)d_in[1];   // (N,S,S,C+5)   f32
    const float* anch = (const float*)d_in[2];   // (B,2)         f32
    float* out  = (float*)d_out;
    float* part = (float*)d_ws;                  // GRID partials (overwritten)

    yolo_loss_kernel<<<GRID, 64, 0, stream>>>(pred, targ, anch, part);
    finalize_kernel<<<1, 1024, 0, stream>>>(part, out);
}